// Round 3
// baseline (312.076 us; speedup 1.0000x reference)
//
#include <hip/hip_runtime.h>
#include <hip/hip_bf16.h>

// GAT fused forward loss.
// e_ij = lrelu(s_i + d_j) is rank-1 => flash-style masked softmax aggregation
// with P built on the fly in bf16, P@Wh via MFMA 16x16x32.
// relu(elu(x)) == relu(x); no softmax max-shift needed (|s+d| < ~8).
// R3: adj read pattern was the limit (65K concurrent 128B-granular streams ->
// random-access HBM at 1.1 TB/s). Split into k_pack (pure sequential stream,
// ballot bit-pack 537MB -> 16.8MB) + k_attn reading the bitmask (cache-resident).

#define NN 8192
#define FTDIM 512
#define CDIM 64
#define NTRAIN 1024
#define LOG2E 1.44269504088896f

typedef __attribute__((ext_vector_type(8))) short short8;
typedef __attribute__((ext_vector_type(4))) float f32x4;
typedef __attribute__((ext_vector_type(4))) int i32x4;
typedef __attribute__((ext_vector_type(2))) unsigned long long u64x2;

static __device__ __forceinline__ unsigned short f2bf(float x) {
    return __bfloat16_as_ushort(__float2bfloat16(x));
}

// ---------------------------------------------------------------------------
// Kernel A: Wh = feat @ W. Each wave computes 8 rows, lane c owns column c.
// Writes Vt[c][j] = bf16(Wh[j][c]) and s,d pre-scaled by log2(e).
// ---------------------------------------------------------------------------
__global__ __launch_bounds__(256) void k_wh(
    const float* __restrict__ feat, const float* __restrict__ W,
    const float* __restrict__ av, unsigned short* __restrict__ Vt,
    float* __restrict__ sv, float* __restrict__ dv)
{
    const int lane = threadIdx.x & 63;
    const int wv   = (int)((blockIdx.x * blockDim.x + threadIdx.x) >> 6);
    const int row0 = wv * 8;
    const int c    = lane;

    float acc[8];
#pragma unroll
    for (int r = 0; r < 8; ++r) acc[r] = 0.f;

    for (int k = 0; k < FTDIM; k += 4) {
        f32x4 f[8];
#pragma unroll
        for (int r = 0; r < 8; ++r)
            f[r] = *(const f32x4*)(feat + (size_t)(row0 + r) * FTDIM + k);
#pragma unroll
        for (int kk = 0; kk < 4; ++kk) {
            float wval = W[(k + kk) * CDIM + c];
#pragma unroll
            for (int r = 0; r < 8; ++r)
                acc[r] = fmaf(f[r][kk], wval, acc[r]);
        }
    }

    short8 v;
#pragma unroll
    for (int r = 0; r < 8; ++r) v[r] = (short)f2bf(acc[r]);
    *(short8*)(Vt + (size_t)c * NN + row0) = v;

    const float a1 = av[c], a2 = av[CDIM + c];
#pragma unroll
    for (int r = 0; r < 8; ++r) {
        float s_ = acc[r] * a1;
        float d_ = acc[r] * a2;
#pragma unroll
        for (int off = 32; off; off >>= 1) {
            s_ += __shfl_xor(s_, off);
            d_ += __shfl_xor(d_, off);
        }
        if (lane == 0) { sv[row0 + r] = s_ * LOG2E; dv[row0 + r] = d_ * LOG2E; }
    }
}

// ---------------------------------------------------------------------------
// Kernel P: bit-pack adjacency. Pure sequential stream (the ONLY way adj is
// read). Per wave-iter: 8 coalesced lane-per-int loads (256B/instr) over 512
// consecutive ints -> 8 ballots -> 64B of mask stored by lane 0.
// maskW bit j of word w == adj_flat[w*32 + j].
// ---------------------------------------------------------------------------
__global__ __launch_bounds__(256) void k_pack(
    const int* __restrict__ adj1, const int* __restrict__ adj2,
    unsigned* __restrict__ maskW)
{
    const int lane = threadIdx.x & 63;
    const int wv = (int)((blockIdx.x * blockDim.x + threadIdx.x) >> 6);
    const int nwaves = (int)((gridDim.x * blockDim.x) >> 6);
    const long long NSQ = (long long)NN * NN;          // 67108864 (pow2)
    const long long totalIters = (2 * NSQ) >> 9;       // 512 ints per iter

    for (long long it = wv; it < totalIters; it += nwaves) {
        const long long base = it << 9;
        const int* __restrict__ src = (base < NSQ) ? adj1 : adj2;
        const long long lbase = base & (NSQ - 1);

        int v0 = src[lbase +   0 + lane];
        int v1 = src[lbase +  64 + lane];
        int v2 = src[lbase + 128 + lane];
        int v3 = src[lbase + 192 + lane];
        int v4 = src[lbase + 256 + lane];
        int v5 = src[lbase + 320 + lane];
        int v6 = src[lbase + 384 + lane];
        int v7 = src[lbase + 448 + lane];

        unsigned long long b0 = __ballot(v0 != 0);
        unsigned long long b1 = __ballot(v1 != 0);
        unsigned long long b2 = __ballot(v2 != 0);
        unsigned long long b3 = __ballot(v3 != 0);
        unsigned long long b4 = __ballot(v4 != 0);
        unsigned long long b5 = __ballot(v5 != 0);
        unsigned long long b6 = __ballot(v6 != 0);
        unsigned long long b7 = __ballot(v7 != 0);

        if (lane == 0) {
            u64x2* dst = (u64x2*)(maskW + (base >> 5));
            dst[0] = u64x2{b0, b1};
            dst[1] = u64x2{b2, b3};
            dst[2] = u64x2{b4, b5};
            dst[3] = u64x2{b6, b7};
        }
    }
}

// ---------------------------------------------------------------------------
// Kernel B: fused masked-softmax aggregation on the bitmask (or raw adj as
// fallback), 2-stage software pipeline. Wave owns 16 rows x one j-chunk.
// Per 32-j tile: 1 mask word/row (+2 d, +4 Vt loads), P = bit ?
// exp2(lrelu(s'+d')) : 0 in bf16 A-frags, 4 MFMAs + VALU row-sum Z.
// Fragment layouts as verified in R1.
// ---------------------------------------------------------------------------
struct TileM {
    unsigned mw;
    i32x4 m0, m1;
    f32x4 d0, d1;
    short8 b0, b1, b2, b3;
};

template<bool USEMASK>
__global__ __launch_bounds__(256) void k_attn(
    const int* __restrict__ adj1, const int* __restrict__ adj2,
    const unsigned* __restrict__ maskW,
    const unsigned short* __restrict__ Vt, const float* __restrict__ sv,
    const float* __restrict__ dvec, float* __restrict__ numP,
    float* __restrict__ zP, const int scLog2)
{
    const int lane = threadIdx.x & 63;
    const int w = (int)((blockIdx.x * blockDim.x + threadIdx.x) >> 6);
    const int layer = w >> (9 + scLog2);
    const int rem = w & ((1 << (9 + scLog2)) - 1);
    const int rb = rem >> scLog2;
    const int sc = rem & ((1 << scLog2) - 1);

    const int r  = lane & 15;
    const int kg = lane >> 4;
    const int i  = rb * 16 + r;

    const int jchunk = NN >> scLog2;
    const int jbase  = sc * jchunk + kg * 8;
    const int niter  = jchunk >> 5;

    const int* __restrict__ adj = (layer == 0) ? adj1 : adj2;
    const int*            arow = adj + (size_t)i * NN + jbase;
    const unsigned*       mrow = maskW + ((size_t)(layer * NN + i) << 8 >> 5 << 5)  // (layer*NN+i)*256
                                 ;
    const unsigned*       mrowp = maskW + (size_t)(layer * NN + i) * (NN >> 5) + sc * (jchunk >> 5);
    const float*          dp   = dvec + jbase;
    const unsigned short* vtp  = Vt + jbase;
    const float s_i = sv[i];
    (void)mrow;

    f32x4 acc0 = {0.f, 0.f, 0.f, 0.f};
    f32x4 acc1 = acc0, acc2 = acc0, acc3 = acc0;
    float z = 0.f;

    TileM tA, tB;

#define LOADT(T, JT) do { const int _off = (JT) * 32;                          \
    if constexpr (USEMASK) { T.mw = mrowp[JT]; }                               \
    else { T.m0 = *(const i32x4*)(arow + _off);                                \
           T.m1 = *(const i32x4*)(arow + _off + 4); }                          \
    T.d0 = *(const f32x4*)(dp + _off);                                         \
    T.d1 = *(const f32x4*)(dp + _off + 4);                                     \
    T.b0 = *(const short8*)(vtp + (size_t)(r) * NN + _off);                    \
    T.b1 = *(const short8*)(vtp + (size_t)(16 + r) * NN + _off);               \
    T.b2 = *(const short8*)(vtp + (size_t)(32 + r) * NN + _off);               \
    T.b3 = *(const short8*)(vtp + (size_t)(48 + r) * NN + _off);               \
} while (0)

#define COMPUTE(T) do {                                                        \
    short8 af; float z0 = 0.f;                                                 \
    unsigned ms = 0;                                                           \
    if constexpr (USEMASK) ms = T.mw >> (kg * 8);                              \
    _Pragma("unroll")                                                          \
    for (int e = 0; e < 4; ++e) {                                              \
        float t = s_i + T.d0[e];                                               \
        float p = __builtin_amdgcn_exp2f(fmaxf(t, 0.2f * t));                  \
        bool on = USEMASK ? ((ms >> e) & 1u) : (T.m0[e] != 0);                 \
        p = on ? p : 0.f;                                                      \
        z0 += p; af[e] = (short)f2bf(p);                                       \
    }                                                                          \
    _Pragma("unroll")                                                          \
    for (int e = 0; e < 4; ++e) {                                              \
        float t = s_i + T.d1[e];                                               \
        float p = __builtin_amdgcn_exp2f(fmaxf(t, 0.2f * t));                  \
        bool on = USEMASK ? ((ms >> (e + 4)) & 1u) : (T.m1[e] != 0);           \
        p = on ? p : 0.f;                                                      \
        z0 += p; af[4 + e] = (short)f2bf(p);                                   \
    }                                                                          \
    z += z0;                                                                   \
    acc0 = __builtin_amdgcn_mfma_f32_16x16x32_bf16(af, T.b0, acc0, 0, 0, 0);   \
    acc1 = __builtin_amdgcn_mfma_f32_16x16x32_bf16(af, T.b1, acc1, 0, 0, 0);   \
    acc2 = __builtin_amdgcn_mfma_f32_16x16x32_bf16(af, T.b2, acc2, 0, 0, 0);   \
    acc3 = __builtin_amdgcn_mfma_f32_16x16x32_bf16(af, T.b3, acc3, 0, 0, 0);   \
} while (0)

    LOADT(tA, 0);
    for (int jt = 0; jt < niter - 2; jt += 2) {
        LOADT(tB, jt + 1);
        COMPUTE(tA);
        LOADT(tA, jt + 2);
        COMPUTE(tB);
    }
    LOADT(tB, niter - 1);
    COMPUTE(tA);
    COMPUTE(tB);

#undef LOADT
#undef COMPUTE

    z += __shfl_xor(z, 16);
    z += __shfl_xor(z, 32);

    const size_t chunkbase = (size_t)((layer << scLog2) + sc) * NN;
    if (kg == 0) zP[chunkbase + i] = z;

    const int orow0 = rb * 16 + kg * 4;
#pragma unroll
    for (int q = 0; q < 4; ++q) {
        float* op = numP + (chunkbase + orow0 + q) * CDIM + r;
        op[0]  = acc0[q];
        op[16] = acc1[q];
        op[32] = acc2[q];
        op[48] = acc3[q];
    }
}

template __global__ void k_attn<true>(const int*, const int*, const unsigned*,
    const unsigned short*, const float*, const float*, float*, float*, const int);
template __global__ void k_attn<false>(const int*, const int*, const unsigned*,
    const unsigned short*, const float*, const float*, float*, float*, const int);

// ---------------------------------------------------------------------------
// Kernel C: per-training-sample loss. One wave per sample, lane = class.
// ---------------------------------------------------------------------------
__global__ __launch_bounds__(256) void k_loss(
    const float* __restrict__ numP, const float* __restrict__ zP,
    const int* __restrict__ labels, const int* __restrict__ idxt,
    float* __restrict__ losses, const int SC)
{
    const int lane = threadIdx.x & 63;
    const int k = (int)((blockIdx.x * blockDim.x + threadIdx.x) >> 6);
    const int i = idxt[k];

    float logit = 0.f;
#pragma unroll
    for (int l = 0; l < 2; ++l) {
        float nsum = 0.f, zsum = 0.f;
        for (int s = 0; s < SC; ++s) {
            size_t b = (size_t)(l * SC + s) * NN + i;
            nsum += numP[b * CDIM + lane];
            zsum += zP[b];
        }
        logit += fmaxf(nsum / zsum, 0.f);   // relu(elu(x)) == relu(x)
    }
    logit *= 0.5f;

    float m = logit;
#pragma unroll
    for (int off = 32; off; off >>= 1) m = fmaxf(m, __shfl_xor(m, off));
    float ex = __expf(logit - m);
    float sum = ex;
#pragma unroll
    for (int off = 32; off; off >>= 1) sum += __shfl_xor(sum, off);
    const float logp = logit - m - __logf(sum);

    const int y = labels[i];
    const float t = __shfl(logp, y);
    if (lane == 0) losses[k] = -t;
}

// ---------------------------------------------------------------------------
// Kernel D: mean of 1024 per-sample losses -> d_out[0].
// ---------------------------------------------------------------------------
__global__ __launch_bounds__(256) void k_reduce(
    const float* __restrict__ losses, float* __restrict__ out)
{
    __shared__ float sbuf[4];
    const int tid = threadIdx.x;
    float v = losses[tid] + losses[tid + 256] + losses[tid + 512] + losses[tid + 768];
#pragma unroll
    for (int off = 32; off; off >>= 1) v += __shfl_xor(v, off);
    if ((tid & 63) == 0) sbuf[tid >> 6] = v;
    __syncthreads();
    if (tid == 0) out[0] = (sbuf[0] + sbuf[1] + sbuf[2] + sbuf[3]) * (1.f / 1024.f);
}

// ---------------------------------------------------------------------------
extern "C" void kernel_launch(void* const* d_in, const int* in_sizes, int n_in,
                              void* d_out, int out_size, void* d_ws, size_t ws_size,
                              hipStream_t stream)
{
    const float* feat   = (const float*)d_in[0];
    const float* W      = (const float*)d_in[1];
    const float* av     = (const float*)d_in[2];
    const int*   adj1   = (const int*)d_in[3];
    const int*   adj2   = (const int*)d_in[4];
    const int*   labels = (const int*)d_in[5];
    const int*   idxt   = (const int*)d_in[6];

    const size_t MASKB = 2ull * NN * (NN / 32) * sizeof(unsigned);  // 16.78 MB

    auto needed = [&](size_t S, bool mask) -> size_t {
        return (1u << 20) + (64u << 10) + (mask ? MASKB : 0)
             + 2 * S * NN * sizeof(float)
             + 2 * S * (size_t)NN * CDIM * sizeof(float)
             + NTRAIN * sizeof(float);
    };

    bool useMask = true;
    int scLog2 = 2;
    if (ws_size < needed(4, true)) {
        if (ws_size >= needed(2, true)) scLog2 = 1;
        else if (ws_size >= needed(1, true)) scLog2 = 0;
        else {
            useMask = false;
            scLog2 = (ws_size >= needed(4, false)) ? 2
                   : (ws_size >= needed(2, false)) ? 1 : 0;
        }
    }
    const int SC = 1 << scLog2;

    char* ws = (char*)d_ws;
    unsigned short* Vt = (unsigned short*)ws;                 // 1 MB
    float* sv = (float*)(ws + (1u << 20));
    float* dv = (float*)(ws + (1u << 20) + (32u << 10));
    char* p = ws + (1u << 20) + (64u << 10);
    unsigned* maskW = (unsigned*)p;
    if (useMask) p += MASKB;
    float* zP   = (float*)p;
    float* numP = (float*)(p + 2 * SC * NN * sizeof(float));
    float* losses = (float*)((char*)numP + 2 * (size_t)SC * NN * CDIM * sizeof(float));

    hipLaunchKernelGGL(k_wh, dim3(256), dim3(256), 0, stream,
                       feat, W, av, Vt, sv, dv);
    if (useMask) {
        hipLaunchKernelGGL(k_pack, dim3(2048), dim3(256), 0, stream,
                           adj1, adj2, maskW);
        hipLaunchKernelGGL((k_attn<true>), dim3(256 * SC), dim3(256), 0, stream,
                           adj1, adj2, maskW, Vt, sv, dv, numP, zP, scLog2);
    } else {
        hipLaunchKernelGGL((k_attn<false>), dim3(256 * SC), dim3(256), 0, stream,
                           adj1, adj2, maskW, Vt, sv, dv, numP, zP, scLog2);
    }
    hipLaunchKernelGGL(k_loss, dim3(NTRAIN / 4), dim3(256), 0, stream,
                       numP, zP, labels, idxt, losses, SC);
    hipLaunchKernelGGL(k_reduce, dim3(1), dim3(256), 0, stream,
                       losses, (float*)d_out);
}

// Round 4
// 268.298 us; speedup vs baseline: 1.1632x; 1.1632x over previous
//
#include <hip/hip_runtime.h>
#include <hip/hip_bf16.h>

// GAT fused forward loss.
// e_ij = lrelu(s_i + d_j) is rank-1 => flash-style masked softmax aggregation
// with P built on the fly in bf16, P@Wh via MFMA 16x16x32.
// relu(elu(x)) == relu(x); no softmax max-shift needed (|s+d| < ~8).
// R4: k_pack with dwordx4 loads + per-lane u16 pack (coalesced stores);
//     k_attn at SC=8 (32 waves/CU) + Vt2 relayout for contiguous L2 lines.

#define NN 8192
#define FTDIM 512
#define CDIM 64
#define NTRAIN 1024
#define LOG2E 1.44269504088896f

typedef __attribute__((ext_vector_type(8))) short short8;
typedef __attribute__((ext_vector_type(4))) float f32x4;
typedef __attribute__((ext_vector_type(4))) int i32x4;

static __device__ __forceinline__ unsigned short f2bf(float x) {
    return __bfloat16_as_ushort(__float2bfloat16(x));
}

// ---------------------------------------------------------------------------
// Kernel A: Wh = feat @ W. Each wave computes 8 rows (one j-block), lane c
// owns column c. Writes Vt2[jblk][c][e] = bf16(Wh[jblk*8+e][c]) — lane c
// stores 16B at offset c*16B -> 1KB fully-coalesced wave store; k_attn's
// 16-lane B-fragment group then reads one contiguous 256B line.
// Also s,d pre-scaled by log2(e) (lrelu commutes with positive scale).
// ---------------------------------------------------------------------------
__global__ __launch_bounds__(256) void k_wh(
    const float* __restrict__ feat, const float* __restrict__ W,
    const float* __restrict__ av, unsigned short* __restrict__ Vt2,
    float* __restrict__ sv, float* __restrict__ dv)
{
    const int lane = threadIdx.x & 63;
    const int wv   = (int)((blockIdx.x * blockDim.x + threadIdx.x) >> 6);
    const int row0 = wv * 8;
    const int c    = lane;

    float acc[8];
#pragma unroll
    for (int r = 0; r < 8; ++r) acc[r] = 0.f;

    for (int k = 0; k < FTDIM; k += 4) {
        f32x4 f[8];
#pragma unroll
        for (int r = 0; r < 8; ++r)
            f[r] = *(const f32x4*)(feat + (size_t)(row0 + r) * FTDIM + k);
#pragma unroll
        for (int kk = 0; kk < 4; ++kk) {
            float wval = W[(k + kk) * CDIM + c];
#pragma unroll
            for (int r = 0; r < 8; ++r)
                acc[r] = fmaf(f[r][kk], wval, acc[r]);
        }
    }

    short8 v;
#pragma unroll
    for (int r = 0; r < 8; ++r) v[r] = (short)f2bf(acc[r]);
    *(short8*)(Vt2 + (size_t)wv * 512 + c * 8) = v;   // [jblk][c][8]

    const float a1 = av[c], a2 = av[CDIM + c];
#pragma unroll
    for (int r = 0; r < 8; ++r) {
        float s_ = acc[r] * a1;
        float d_ = acc[r] * a2;
#pragma unroll
        for (int off = 32; off; off >>= 1) {
            s_ += __shfl_xor(s_, off);
            d_ += __shfl_xor(d_, off);
        }
        if (lane == 0) { sv[row0 + r] = s_ * LOG2E; dv[row0 + r] = d_ * LOG2E; }
    }
}

// ---------------------------------------------------------------------------
// Kernel P: bit-pack adjacency. Pure sequential stream, 64B/lane/iter via
// 4x dwordx4; each lane covers 16 CONSECUTIVE j -> one u16 mask packed
// in-register, stored coalesced (64 lanes x 2B = 128B/wave store).
// Layout as u32 words: bit b of word w == adj_flat[w*32 + b] (same as R3).
// ---------------------------------------------------------------------------
__global__ __launch_bounds__(256) void k_pack(
    const int* __restrict__ adj1, const int* __restrict__ adj2,
    unsigned short* __restrict__ maskB)
{
    const int lane = threadIdx.x & 63;
    const int wv = (int)((blockIdx.x * blockDim.x + threadIdx.x) >> 6);
    const int nwaves = (int)((gridDim.x * blockDim.x) >> 6);
    const long long NSQ = (long long)NN * NN;          // 2^26
    const long long totalIters = (2 * NSQ) >> 10;      // 1024 ints per iter

    for (long long it = wv; it < totalIters; it += nwaves) {
        const long long base = it << 10;
        const int* __restrict__ src = (base < NSQ) ? adj1 : adj2;
        const long long lbase = (base & (NSQ - 1)) + (long long)lane * 16;

        i32x4 a0 = *(const i32x4*)(src + lbase);
        i32x4 a1 = *(const i32x4*)(src + lbase + 4);
        i32x4 a2 = *(const i32x4*)(src + lbase + 8);
        i32x4 a3 = *(const i32x4*)(src + lbase + 12);

        unsigned m = 0;
#pragma unroll
        for (int e = 0; e < 4; ++e) {
            m |= (a0[e] != 0 ? 1u : 0u) << e;
            m |= (a1[e] != 0 ? 1u : 0u) << (4 + e);
            m |= (a2[e] != 0 ? 1u : 0u) << (8 + e);
            m |= (a3[e] != 0 ? 1u : 0u) << (12 + e);
        }
        maskB[(base >> 4) + lane] = (unsigned short)m;
    }
}

// ---------------------------------------------------------------------------
// Kernel B: fused masked-softmax aggregation on the bitmask (raw-adj
// fallback), 2-stage software pipeline. Wave owns 16 rows x one j-chunk.
// Per 32-j tile: 1 mask word/row + 2 d-f32x4 (L1 broadcast) + 4 contiguous
// Vt2 short8; P = bit ? exp2(lrelu(s'+d')) : 0 in bf16 A-frags; 4 MFMAs +
// VALU row-sum Z. SC=8 -> 8192 waves (32/CU); launch_bounds(256,8) pins
// VGPR <= 64 for 8 waves/SIMD. Fragment layouts verified in R1.
// ---------------------------------------------------------------------------
struct TileM {
    unsigned mw;
    i32x4 m0, m1;
    f32x4 d0, d1;
    short8 b0, b1, b2, b3;
};

template<bool USEMASK>
__global__ __launch_bounds__(256, 8) void k_attn(
    const int* __restrict__ adj1, const int* __restrict__ adj2,
    const unsigned* __restrict__ maskW,
    const unsigned short* __restrict__ Vt2, const float* __restrict__ sv,
    const float* __restrict__ dvec, float* __restrict__ numP,
    float* __restrict__ zP, const int scLog2)
{
    const int lane = threadIdx.x & 63;
    const int w = (int)((blockIdx.x * blockDim.x + threadIdx.x) >> 6);
    const int layer = w >> (9 + scLog2);
    const int rem = w & ((1 << (9 + scLog2)) - 1);
    const int rb = rem >> scLog2;
    const int sc = rem & ((1 << scLog2) - 1);

    const int r  = lane & 15;
    const int kg = lane >> 4;
    const int i  = rb * 16 + r;

    const int jchunk = NN >> scLog2;
    const int jbase  = sc * jchunk + kg * 8;
    const int niter  = jchunk >> 5;           // >= 32, even

    const int* __restrict__ adj = (layer == 0) ? adj1 : adj2;
    const int*            arow  = adj + (size_t)i * NN + jbase;
    const unsigned*       mrowp = maskW + (size_t)(layer * NN + i) * (NN >> 5)
                                        + sc * (jchunk >> 5);
    const float*          dp    = dvec + jbase;
    // Vt2 base for this lane: j-block (jbase>>3), row r within c-block
    const unsigned short* vt2p  = Vt2 + (((size_t)jbase >> 3) << 9) + ((size_t)r << 3);
    const float s_i = sv[i];

    f32x4 acc0 = {0.f, 0.f, 0.f, 0.f};
    f32x4 acc1 = acc0, acc2 = acc0, acc3 = acc0;
    float z = 0.f;

    TileM tA, tB;

#define LOADT(T, JT) do { const int _off = (JT) * 32;                          \
    const unsigned short* _vp = vt2p + (size_t)(JT) * 2048;                    \
    if constexpr (USEMASK) { T.mw = mrowp[JT]; }                               \
    else { T.m0 = *(const i32x4*)(arow + _off);                                \
           T.m1 = *(const i32x4*)(arow + _off + 4); }                          \
    T.d0 = *(const f32x4*)(dp + _off);                                         \
    T.d1 = *(const f32x4*)(dp + _off + 4);                                     \
    T.b0 = *(const short8*)(_vp);                                              \
    T.b1 = *(const short8*)(_vp + 128);                                        \
    T.b2 = *(const short8*)(_vp + 256);                                        \
    T.b3 = *(const short8*)(_vp + 384);                                        \
} while (0)

#define COMPUTE(T) do {                                                        \
    short8 af; float z0 = 0.f;                                                 \
    unsigned ms = 0;                                                           \
    if constexpr (USEMASK) ms = T.mw >> (kg * 8);                              \
    _Pragma("unroll")                                                          \
    for (int e = 0; e < 4; ++e) {                                              \
        float t = s_i + T.d0[e];                                               \
        float p = __builtin_amdgcn_exp2f(fmaxf(t, 0.2f * t));                  \
        bool on = USEMASK ? ((ms >> e) & 1u) : (T.m0[e] != 0);                 \
        p = on ? p : 0.f;                                                      \
        z0 += p; af[e] = (short)f2bf(p);                                       \
    }                                                                          \
    _Pragma("unroll")                                                          \
    for (int e = 0; e < 4; ++e) {                                              \
        float t = s_i + T.d1[e];                                               \
        float p = __builtin_amdgcn_exp2f(fmaxf(t, 0.2f * t));                  \
        bool on = USEMASK ? ((ms >> (e + 4)) & 1u) : (T.m1[e] != 0);           \
        p = on ? p : 0.f;                                                      \
        z0 += p; af[4 + e] = (short)f2bf(p);                                   \
    }                                                                          \
    z += z0;                                                                   \
    acc0 = __builtin_amdgcn_mfma_f32_16x16x32_bf16(af, T.b0, acc0, 0, 0, 0);   \
    acc1 = __builtin_amdgcn_mfma_f32_16x16x32_bf16(af, T.b1, acc1, 0, 0, 0);   \
    acc2 = __builtin_amdgcn_mfma_f32_16x16x32_bf16(af, T.b2, acc2, 0, 0, 0);   \
    acc3 = __builtin_amdgcn_mfma_f32_16x16x32_bf16(af, T.b3, acc3, 0, 0, 0);   \
} while (0)

    LOADT(tA, 0);
    for (int jt = 0; jt < niter - 2; jt += 2) {
        LOADT(tB, jt + 1);
        COMPUTE(tA);
        LOADT(tA, jt + 2);
        COMPUTE(tB);
    }
    LOADT(tB, niter - 1);
    COMPUTE(tA);
    COMPUTE(tB);

#undef LOADT
#undef COMPUTE

    z += __shfl_xor(z, 16);
    z += __shfl_xor(z, 32);

    const size_t chunkbase = (size_t)((layer << scLog2) + sc) * NN;
    if (kg == 0) zP[chunkbase + i] = z;

    const int orow0 = rb * 16 + kg * 4;
#pragma unroll
    for (int q = 0; q < 4; ++q) {
        float* op = numP + (chunkbase + orow0 + q) * CDIM + r;
        op[0]  = acc0[q];
        op[16] = acc1[q];
        op[32] = acc2[q];
        op[48] = acc3[q];
    }
}

template __global__ void k_attn<true>(const int*, const int*, const unsigned*,
    const unsigned short*, const float*, const float*, float*, float*, const int);
template __global__ void k_attn<false>(const int*, const int*, const unsigned*,
    const unsigned short*, const float*, const float*, float*, float*, const int);

// ---------------------------------------------------------------------------
// Kernel C: per-training-sample loss. One wave per sample, lane = class.
// ---------------------------------------------------------------------------
__global__ __launch_bounds__(256) void k_loss(
    const float* __restrict__ numP, const float* __restrict__ zP,
    const int* __restrict__ labels, const int* __restrict__ idxt,
    float* __restrict__ losses, const int SC)
{
    const int lane = threadIdx.x & 63;
    const int k = (int)((blockIdx.x * blockDim.x + threadIdx.x) >> 6);
    const int i = idxt[k];

    float logit = 0.f;
#pragma unroll
    for (int l = 0; l < 2; ++l) {
        float nsum = 0.f, zsum = 0.f;
        for (int s = 0; s < SC; ++s) {
            size_t b = (size_t)(l * SC + s) * NN + i;
            nsum += numP[b * CDIM + lane];
            zsum += zP[b];
        }
        logit += fmaxf(nsum / zsum, 0.f);   // relu(elu(x)) == relu(x)
    }
    logit *= 0.5f;

    float m = logit;
#pragma unroll
    for (int off = 32; off; off >>= 1) m = fmaxf(m, __shfl_xor(m, off));
    float ex = __expf(logit - m);
    float sum = ex;
#pragma unroll
    for (int off = 32; off; off >>= 1) sum += __shfl_xor(sum, off);
    const float logp = logit - m - __logf(sum);

    const int y = labels[i];
    const float t = __shfl(logp, y);
    if (lane == 0) losses[k] = -t;
}

// ---------------------------------------------------------------------------
// Kernel D: mean of 1024 per-sample losses -> d_out[0].
// ---------------------------------------------------------------------------
__global__ __launch_bounds__(256) void k_reduce(
    const float* __restrict__ losses, float* __restrict__ out)
{
    __shared__ float sbuf[4];
    const int tid = threadIdx.x;
    float v = losses[tid] + losses[tid + 256] + losses[tid + 512] + losses[tid + 768];
#pragma unroll
    for (int off = 32; off; off >>= 1) v += __shfl_xor(v, off);
    if ((tid & 63) == 0) sbuf[tid >> 6] = v;
    __syncthreads();
    if (tid == 0) out[0] = (sbuf[0] + sbuf[1] + sbuf[2] + sbuf[3]) * (1.f / 1024.f);
}

// ---------------------------------------------------------------------------
extern "C" void kernel_launch(void* const* d_in, const int* in_sizes, int n_in,
                              void* d_out, int out_size, void* d_ws, size_t ws_size,
                              hipStream_t stream)
{
    const float* feat   = (const float*)d_in[0];
    const float* W      = (const float*)d_in[1];
    const float* av     = (const float*)d_in[2];
    const int*   adj1   = (const int*)d_in[3];
    const int*   adj2   = (const int*)d_in[4];
    const int*   labels = (const int*)d_in[5];
    const int*   idxt   = (const int*)d_in[6];

    const size_t MASKB = 2ull * NN * (NN / 32) * sizeof(unsigned);  // 16.78 MB

    auto needed = [&](size_t S, bool mask) -> size_t {
        return (1u << 20) + (64u << 10) + (mask ? MASKB : 0)
             + 2 * S * NN * sizeof(float)
             + 2 * S * (size_t)NN * CDIM * sizeof(float)
             + NTRAIN * sizeof(float);
    };

    bool useMask = false;
    int scLog2 = 0;
    for (int s = 3; s >= 0; --s)
        if (ws_size >= needed((size_t)1 << s, true)) { useMask = true; scLog2 = s; break; }
    if (!useMask) {
        scLog2 = (ws_size >= needed(4, false)) ? 2
               : (ws_size >= needed(2, false)) ? 1 : 0;
    }
    const int SC = 1 << scLog2;

    char* ws = (char*)d_ws;
    unsigned short* Vt2 = (unsigned short*)ws;                 // 1 MB
    float* sv = (float*)(ws + (1u << 20));
    float* dv = (float*)(ws + (1u << 20) + (32u << 10));
    char* p = ws + (1u << 20) + (64u << 10);
    unsigned* maskW = (unsigned*)p;
    if (useMask) p += MASKB;
    float* zP   = (float*)p;
    float* numP = (float*)(p + 2 * SC * NN * sizeof(float));
    float* losses = (float*)((char*)numP + 2 * (size_t)SC * NN * CDIM * sizeof(float));

    hipLaunchKernelGGL(k_wh, dim3(256), dim3(256), 0, stream,
                       feat, W, av, Vt2, sv, dv);
    if (useMask) {
        hipLaunchKernelGGL(k_pack, dim3(2048), dim3(256), 0, stream,
                           adj1, adj2, (unsigned short*)maskW);
        hipLaunchKernelGGL((k_attn<true>), dim3(256 * SC), dim3(256), 0, stream,
                           adj1, adj2, maskW, Vt2, sv, dv, numP, zP, scLog2);
    } else {
        hipLaunchKernelGGL((k_attn<false>), dim3(256 * SC), dim3(256), 0, stream,
                           adj1, adj2, maskW, Vt2, sv, dv, numP, zP, scLog2);
    }
    hipLaunchKernelGGL(k_loss, dim3(NTRAIN / 4), dim3(256), 0, stream,
                       numP, zP, labels, idxt, losses, SC);
    hipLaunchKernelGGL(k_reduce, dim3(1), dim3(256), 0, stream,
                       losses, (float*)d_out);
}

// Round 5
// 265.564 us; speedup vs baseline: 1.1751x; 1.0103x over previous
//
#include <hip/hip_runtime.h>
#include <hip/hip_bf16.h>

// GAT fused forward loss.
// e_ij = lrelu(s_i + d_j) is rank-1 => flash-style masked softmax aggregation
// with P built on the fly in bf16, P@Wh via MFMA 16x16x32.
// relu(elu(x)) == relu(x); no softmax max-shift needed (|s+d| < ~8).
// R5: k_attn single-tile + (256,6) (no spill, 24 waves/CU), factored exp
//     (P = sel(e1d>th ? E1*e1d : E2*e2d) -- no transcendental in loop),
//     Z via 5th MFMA with B=ones (idle matrix pipe does the row-sum).
//     k_pack: fixed 8-iter schedule, unroll 4 -> 16 dwordx4 in flight.

#define NN 8192
#define FTDIM 512
#define CDIM 64
#define NTRAIN 1024
#define LOG2E 1.44269504088896f

typedef __attribute__((ext_vector_type(8))) short short8;
typedef __attribute__((ext_vector_type(4))) float f32x4;
typedef __attribute__((ext_vector_type(4))) int i32x4;

static __device__ __forceinline__ unsigned short f2bf(float x) {
    return __bfloat16_as_ushort(__float2bfloat16(x));
}

// ---------------------------------------------------------------------------
// Kernel A: Wh = feat @ W. Each wave computes 8 rows (one j-block), lane c
// owns column c. Writes Vt2[jblk][c][e] = bf16(Wh[jblk*8+e][c]) (contiguous
// 256B per 16-lane B-fragment group in k_attn). Stores factored-exp tables:
//   sQ[i] = (E1, E2, th) = (2^s', 2^(0.2 s'), 2^(-s'))
//   dE[j] = (e1, e2)     = (2^d', 2^(0.2 d'))     with s',d' = log2e-scaled.
// Then P = (e1d > th) ? E1*e1d : E2*e2d  ==  exp(lrelu(s+d)) exactly.
// ---------------------------------------------------------------------------
__global__ __launch_bounds__(256) void k_wh(
    const float* __restrict__ feat, const float* __restrict__ W,
    const float* __restrict__ av, unsigned short* __restrict__ Vt2,
    float4* __restrict__ sQ, float2* __restrict__ dE)
{
    const int lane = threadIdx.x & 63;
    const int wv   = (int)((blockIdx.x * blockDim.x + threadIdx.x) >> 6);
    const int row0 = wv * 8;
    const int c    = lane;

    float acc[8];
#pragma unroll
    for (int r = 0; r < 8; ++r) acc[r] = 0.f;

    for (int k = 0; k < FTDIM; k += 4) {
        f32x4 f[8];
#pragma unroll
        for (int r = 0; r < 8; ++r)
            f[r] = *(const f32x4*)(feat + (size_t)(row0 + r) * FTDIM + k);
#pragma unroll
        for (int kk = 0; kk < 4; ++kk) {
            float wval = W[(k + kk) * CDIM + c];
#pragma unroll
            for (int r = 0; r < 8; ++r)
                acc[r] = fmaf(f[r][kk], wval, acc[r]);
        }
    }

    short8 v;
#pragma unroll
    for (int r = 0; r < 8; ++r) v[r] = (short)f2bf(acc[r]);
    *(short8*)(Vt2 + (size_t)wv * 512 + c * 8) = v;   // [jblk][c][8]

    const float a1 = av[c], a2 = av[CDIM + c];
#pragma unroll
    for (int r = 0; r < 8; ++r) {
        float s_ = acc[r] * a1;
        float d_ = acc[r] * a2;
#pragma unroll
        for (int off = 32; off; off >>= 1) {
            s_ += __shfl_xor(s_, off);
            d_ += __shfl_xor(d_, off);
        }
        if (lane == 0) {
            const float sp = s_ * LOG2E, dp_ = d_ * LOG2E;
            sQ[row0 + r] = make_float4(__builtin_amdgcn_exp2f(sp),
                                       __builtin_amdgcn_exp2f(0.2f * sp),
                                       __builtin_amdgcn_exp2f(-sp), 0.f);
            dE[row0 + r] = make_float2(__builtin_amdgcn_exp2f(dp_),
                                       __builtin_amdgcn_exp2f(0.2f * dp_));
        }
    }
}

// ---------------------------------------------------------------------------
// Kernel P: bit-pack adjacency. Pure sequential stream. Grid FIXED at
// 4096x256 => 16384 waves; 2*NN*NN/1024 = 131072 wave-iters => exactly 8
// per wave. unroll 4 -> 16 dwordx4 (256B/lane) outstanding per wave.
// Per iter: 1024 consecutive ints -> 64 u16 masks stored coalesced.
// Bit b of u32 word w == adj_flat[w*32 + b].
// ---------------------------------------------------------------------------
__global__ __launch_bounds__(256, 4) void k_pack(
    const int* __restrict__ adj1, const int* __restrict__ adj2,
    unsigned short* __restrict__ maskB)
{
    const int lane = threadIdx.x & 63;
    const int wv = (int)((blockIdx.x * blockDim.x + threadIdx.x) >> 6);
    const long long NSQ = (long long)NN * NN;          // 2^26

#pragma unroll 4
    for (int u = 0; u < 8; ++u) {
        const long long it = (long long)wv + (long long)u * 16384;
        const long long base = it << 10;
        const int* __restrict__ src = (base < NSQ) ? adj1 : adj2;
        const long long lbase = (base & (NSQ - 1)) + (long long)lane * 16;

        i32x4 a0 = *(const i32x4*)(src + lbase);
        i32x4 a1 = *(const i32x4*)(src + lbase + 4);
        i32x4 a2 = *(const i32x4*)(src + lbase + 8);
        i32x4 a3 = *(const i32x4*)(src + lbase + 12);

        unsigned m = 0;
#pragma unroll
        for (int e = 0; e < 4; ++e) {
            m |= (a0[e] != 0 ? 1u : 0u) << e;
            m |= (a1[e] != 0 ? 1u : 0u) << (4 + e);
            m |= (a2[e] != 0 ? 1u : 0u) << (8 + e);
            m |= (a3[e] != 0 ? 1u : 0u) << (12 + e);
        }
        maskB[(base >> 4) + lane] = (unsigned short)m;
    }
}

// ---------------------------------------------------------------------------
// Kernel B: fused masked-softmax aggregation on the bitmask (raw-adj
// fallback). Wave owns 16 rows x one j-chunk (SC=8 -> 8192 waves, 24+/CU at
// (256,6)). Per 32-j tile, per lane: 1 mask word + 4 dE f32x4 + 4 Vt2 short8
// (9 independent loads, no barriers -> TLP hides L2 latency); P built with
// {cmp, cndmask x2, mul} per element (factored exp, no transcendental);
// 4 MFMAs for numP + 1 MFMA vs B=ones for Z (matrix pipe was 4% busy).
// Fragment layouts verified in R1.
// ---------------------------------------------------------------------------
template<bool USEMASK>
__global__ __launch_bounds__(256, 6) void k_attn(
    const int* __restrict__ adj1, const int* __restrict__ adj2,
    const unsigned* __restrict__ maskW,
    const unsigned short* __restrict__ Vt2, const float4* __restrict__ sQ,
    const float2* __restrict__ dE, float* __restrict__ numP,
    float* __restrict__ zP, const int scLog2)
{
    const int lane = threadIdx.x & 63;
    const int w = (int)((blockIdx.x * blockDim.x + threadIdx.x) >> 6);
    const int layer = w >> (9 + scLog2);
    const int rem = w & ((1 << (9 + scLog2)) - 1);
    const int rb = rem >> scLog2;
    const int sc = rem & ((1 << scLog2) - 1);

    const int r  = lane & 15;
    const int kg = lane >> 4;
    const int i  = rb * 16 + r;

    const int jchunk = NN >> scLog2;
    const int jbase  = sc * jchunk + kg * 8;
    const int niter  = jchunk >> 5;

    const int* __restrict__ adj = (layer == 0) ? adj1 : adj2;
    const int*            arow  = adj + (size_t)i * NN + jbase;
    const unsigned*       mrowp = maskW + (size_t)(layer * NN + i) * (NN >> 5)
                                        + sc * (jchunk >> 5);
    const f32x4*          dEp   = (const f32x4*)(dE + jbase);  // 4 f32x4 = lane's 8 (e1,e2)
    const unsigned short* vt2p  = Vt2 + (((size_t)jbase >> 3) << 9) + ((size_t)r << 3);

    const float4 sq = sQ[i];
    const float E1 = sq.x, E2 = sq.y, th = sq.z;

    // B = ones fragment for the Z row-sum MFMA (bf16 1.0 = 0x3F80)
    short8 bOnes;
#pragma unroll
    for (int e = 0; e < 8; ++e) bOnes[e] = (short)0x3F80;

    f32x4 acc0 = {0.f, 0.f, 0.f, 0.f};
    f32x4 acc1 = acc0, acc2 = acc0, acc3 = acc0, accz = acc0;

    for (int jt = 0; jt < niter; ++jt) {
        unsigned mw = 0;
        i32x4 m0, m1;
        if constexpr (USEMASK) {
            mw = mrowp[jt];
        } else {
            m0 = *(const i32x4*)(arow + jt * 32);
            m1 = *(const i32x4*)(arow + jt * 32 + 4);
        }
        const f32x4* dp = dEp + (size_t)jt * 8;   // 32 j * float2 = 8 f32x4; ours: 4
        f32x4 q0 = dp[0], q1 = dp[1], q2 = dp[2], q3 = dp[3];
        const unsigned short* vp = vt2p + (size_t)jt * 2048;
        short8 b0 = *(const short8*)(vp);
        short8 b1 = *(const short8*)(vp + 128);
        short8 b2 = *(const short8*)(vp + 256);
        short8 b3 = *(const short8*)(vp + 384);

        const unsigned ms = USEMASK ? (mw >> (kg * 8)) : 0u;
        short8 af;
#pragma unroll
        for (int e = 0; e < 8; ++e) {
            float e1, e2;
            switch (e >> 1) {
                case 0: e1 = q0[(e & 1) * 2]; e2 = q0[(e & 1) * 2 + 1]; break;
                case 1: e1 = q1[(e & 1) * 2]; e2 = q1[(e & 1) * 2 + 1]; break;
                case 2: e1 = q2[(e & 1) * 2]; e2 = q2[(e & 1) * 2 + 1]; break;
                default: e1 = q3[(e & 1) * 2]; e2 = q3[(e & 1) * 2 + 1]; break;
            }
            const bool pos = e1 > th;                 // <=> s'+d' > 0
            float p = (pos ? e1 : e2) * (pos ? E1 : E2);
            const bool on = USEMASK ? (((ms >> e) & 1u) != 0u)
                                    : ((e < 4 ? m0[e] : m1[e - 4]) != 0);
            p = on ? p : 0.f;
            af[e] = (short)f2bf(p);
        }

        acc0 = __builtin_amdgcn_mfma_f32_16x16x32_bf16(af, b0, acc0, 0, 0, 0);
        acc1 = __builtin_amdgcn_mfma_f32_16x16x32_bf16(af, b1, acc1, 0, 0, 0);
        acc2 = __builtin_amdgcn_mfma_f32_16x16x32_bf16(af, b2, acc2, 0, 0, 0);
        acc3 = __builtin_amdgcn_mfma_f32_16x16x32_bf16(af, b3, acc3, 0, 0, 0);
        accz = __builtin_amdgcn_mfma_f32_16x16x32_bf16(af, bOnes, accz, 0, 0, 0);
    }

    const size_t chunkbase = (size_t)((layer << scLog2) + sc) * NN;
    const int orow0 = rb * 16 + kg * 4;

    // accz[q] = Z of row (kg*4+q), identical across the 16 col-lanes.
    if (r == 0) {
#pragma unroll
        for (int q = 0; q < 4; ++q) zP[chunkbase + orow0 + q] = accz[q];
    }

#pragma unroll
    for (int q = 0; q < 4; ++q) {
        float* op = numP + (chunkbase + orow0 + q) * CDIM + r;
        op[0]  = acc0[q];
        op[16] = acc1[q];
        op[32] = acc2[q];
        op[48] = acc3[q];
    }
}

template __global__ void k_attn<true>(const int*, const int*, const unsigned*,
    const unsigned short*, const float4*, const float2*, float*, float*, const int);
template __global__ void k_attn<false>(const int*, const int*, const unsigned*,
    const unsigned short*, const float4*, const float2*, float*, float*, const int);

// ---------------------------------------------------------------------------
// Kernel C: per-training-sample loss. One wave per sample, lane = class.
// ---------------------------------------------------------------------------
__global__ __launch_bounds__(256) void k_loss(
    const float* __restrict__ numP, const float* __restrict__ zP,
    const int* __restrict__ labels, const int* __restrict__ idxt,
    float* __restrict__ losses, const int SC)
{
    const int lane = threadIdx.x & 63;
    const int k = (int)((blockIdx.x * blockDim.x + threadIdx.x) >> 6);
    const int i = idxt[k];

    float logit = 0.f;
#pragma unroll
    for (int l = 0; l < 2; ++l) {
        float nsum = 0.f, zsum = 0.f;
        for (int s = 0; s < SC; ++s) {
            size_t b = (size_t)(l * SC + s) * NN + i;
            nsum += numP[b * CDIM + lane];
            zsum += zP[b];
        }
        logit += fmaxf(nsum / zsum, 0.f);   // relu(elu(x)) == relu(x)
    }
    logit *= 0.5f;

    float m = logit;
#pragma unroll
    for (int off = 32; off; off >>= 1) m = fmaxf(m, __shfl_xor(m, off));
    float ex = __expf(logit - m);
    float sum = ex;
#pragma unroll
    for (int off = 32; off; off >>= 1) sum += __shfl_xor(sum, off);
    const float logp = logit - m - __logf(sum);

    const int y = labels[i];
    const float t = __shfl(logp, y);
    if (lane == 0) losses[k] = -t;
}

// ---------------------------------------------------------------------------
// Kernel D: mean of 1024 per-sample losses -> d_out[0].
// ---------------------------------------------------------------------------
__global__ __launch_bounds__(256) void k_reduce(
    const float* __restrict__ losses, float* __restrict__ out)
{
    __shared__ float sbuf[4];
    const int tid = threadIdx.x;
    float v = losses[tid] + losses[tid + 256] + losses[tid + 512] + losses[tid + 768];
#pragma unroll
    for (int off = 32; off; off >>= 1) v += __shfl_xor(v, off);
    if ((tid & 63) == 0) sbuf[tid >> 6] = v;
    __syncthreads();
    if (tid == 0) out[0] = (sbuf[0] + sbuf[1] + sbuf[2] + sbuf[3]) * (1.f / 1024.f);
}

// ---------------------------------------------------------------------------
extern "C" void kernel_launch(void* const* d_in, const int* in_sizes, int n_in,
                              void* d_out, int out_size, void* d_ws, size_t ws_size,
                              hipStream_t stream)
{
    const float* feat   = (const float*)d_in[0];
    const float* W      = (const float*)d_in[1];
    const float* av     = (const float*)d_in[2];
    const int*   adj1   = (const int*)d_in[3];
    const int*   adj2   = (const int*)d_in[4];
    const int*   labels = (const int*)d_in[5];
    const int*   idxt   = (const int*)d_in[6];

    const size_t MASKB = 2ull * NN * (NN / 32) * sizeof(unsigned);  // 16.78 MB
    const size_t HEAD  = (1u << 20) + (192u << 10);  // Vt2 1MB + sQ 128KB + dE 64KB

    auto needed = [&](size_t S, bool mask) -> size_t {
        return HEAD + (mask ? MASKB : 0)
             + 2 * S * NN * sizeof(float)
             + 2 * S * (size_t)NN * CDIM * sizeof(float)
             + NTRAIN * sizeof(float);
    };

    bool useMask = false;
    int scLog2 = 0;
    for (int s = 3; s >= 0; --s)
        if (ws_size >= needed((size_t)1 << s, true)) { useMask = true; scLog2 = s; break; }
    if (!useMask) {
        scLog2 = (ws_size >= needed(4, false)) ? 2
               : (ws_size >= needed(2, false)) ? 1 : 0;
    }
    const int SC = 1 << scLog2;

    char* ws = (char*)d_ws;
    unsigned short* Vt2 = (unsigned short*)ws;                 // 1 MB
    float4* sQ = (float4*)(ws + (1u << 20));                   // 128 KB
    float2* dEv = (float2*)(ws + (1u << 20) + (128u << 10));   // 64 KB
    char* p = ws + HEAD;
    unsigned* maskW = (unsigned*)p;
    if (useMask) p += MASKB;
    float* zP   = (float*)p;
    float* numP = (float*)(p + 2 * SC * NN * sizeof(float));
    float* losses = (float*)((char*)numP + 2 * (size_t)SC * NN * CDIM * sizeof(float));

    hipLaunchKernelGGL(k_wh, dim3(256), dim3(256), 0, stream,
                       feat, W, av, Vt2, sQ, dEv);
    if (useMask) {
        hipLaunchKernelGGL(k_pack, dim3(4096), dim3(256), 0, stream,
                           adj1, adj2, (unsigned short*)maskW);
        hipLaunchKernelGGL((k_attn<true>), dim3(256 * SC), dim3(256), 0, stream,
                           adj1, adj2, maskW, Vt2, sQ, dEv, numP, zP, scLog2);
    } else {
        hipLaunchKernelGGL((k_attn<false>), dim3(256 * SC), dim3(256), 0, stream,
                           adj1, adj2, maskW, Vt2, sQ, dEv, numP, zP, scLog2);
    }
    hipLaunchKernelGGL(k_loss, dim3(NTRAIN / 4), dim3(256), 0, stream,
                       numP, zP, labels, idxt, losses, SC);
    hipLaunchKernelGGL(k_reduce, dim3(1), dim3(256), 0, stream,
                       losses, (float*)d_out);
}